// Round 14
// baseline (282.696 us; speedup 1.0000x reference)
//
#include <hip/hip_runtime.h>
#include <hip/hip_bf16.h>
#include <math.h>

#define LN_EPS 1e-5f
// dim^-0.5 * log2(e): folded into q so softmax is exp2(s) with no muls
#define QSCALE 0.09016844005556021f

typedef __attribute__((ext_vector_type(8))) short short8;
typedef __attribute__((ext_vector_type(4))) short short4v;
typedef __attribute__((ext_vector_type(4))) float f32x4;
typedef __attribute__((ext_vector_type(16))) float f32x16;

__device__ inline ushort f2bf(float f) {
  __hip_bfloat16 h = __float2bfloat16(f);
  return *reinterpret_cast<ushort*>(&h);
}

// pack two positive fp32 into bf16 pair (lo=a, hi=b): +0x8000 then v_perm.
// (hardware-verified; do NOT swap for cvt_pk asm)
__device__ inline uint pk2bf(float a, float b) {
  uint ua = __float_as_uint(a) + 0x8000u;
  uint ub = __float_as_uint(b) + 0x8000u;
  return __builtin_amdgcn_perm(ub, ua, 0x07060302u);
}

// Shapes (fixed): b=8, n=2048/stream, 3 streams, dim=256, heads=8, d=32.
// xn (bf16): [8*6144][256].  q/k (bf16): [bh][2048][32] row-major -- these
//   double as 32x32x16 MFMA A/B fragment sources (row=lane&31, k=hi*8+i).
// vT3 (bf16, 32x32 B-FRAGMENT layout): [bh][64 ktile32][2 u][64 lane][8]:
//   elem = V[key = ktile*32 + 16u + (i&3) + 8*(i>>2) + 4*(lane>>5)]
//            [d = lane&31]  (key perm == 32x32 MFMA C-row pattern, so attn's
//   P-register file feeds PV's A operand with NO data movement).
// osum_e / osum_l (bf16): [b*2048][256] (osum_l aliases dead xn region).
// ROUND 14: attn plateaued across 6 variants (116-120us) -- structural.
// The NON-attn residue (154us vs ~50us roofline) is the target now:
// proj ran 3 blocks/CU and outproj 2 blocks/CU (latency-bound, same
// disease attn had in r3-r5).  Halve tokens/block in both: proj 128->64
// (grid 1536 = 6/CU), outproj 64->32 (grid 1024 = 4/CU).  No numerics
// change anywhere; attn byte-identical to r13 as control.

// ---------------------- fused: LN-normalize -> bf16  +  weight cast -> bf16
__global__ __launch_bounds__(256) void ln_wcast_kernel(
    const float* __restrict__ x, const float* __restrict__ lng,
    const float* __restrict__ lnb,
    const float* __restrict__ Wq, const float* __restrict__ Wk,
    const float* __restrict__ Wv, const float* __restrict__ Wo,
    ushort* __restrict__ xn, ushort* __restrict__ wbf) {
  if (blockIdx.x < 256) {
    int t = blockIdx.x * 256 + threadIdx.x;
    int e0 = t * 4;
    int m = e0 >> 16, off = e0 & 65535;
    const float* src = (m == 0) ? Wq : (m == 1) ? Wk : (m == 2) ? Wv : Wo;
    float4 v = *(const float4*)(src + off);
    ushort4 o;
    o.x = f2bf(v.x); o.y = f2bf(v.y); o.z = f2bf(v.z); o.w = f2bf(v.w);
    *(ushort4*)(wbf + m * 65536 + off) = o;
    return;
  }
  int w = threadIdx.x >> 6;
  int lane = threadIdx.x & 63;
  size_t token = (size_t)(blockIdx.x - 256) * 4 + w;
  float4 v = *(const float4*)(x + token * 256 + lane * 4);
  float s  = v.x + v.y + v.z + v.w;
  float s2 = v.x * v.x + v.y * v.y + v.z * v.z + v.w * v.w;
#pragma unroll
  for (int off = 32; off >= 1; off >>= 1) {
    s  += __shfl_xor(s, off, 64);
    s2 += __shfl_xor(s2, off, 64);
  }
  float mu  = s * (1.0f / 256.0f);
  float var = s2 * (1.0f / 256.0f) - mu * mu;
  float rs  = rsqrtf(var + LN_EPS);
  float4 g = *(const float4*)(lng + lane * 4);
  float4 bb = *(const float4*)(lnb + lane * 4);
  ushort4 o;
  o.x = f2bf((v.x - mu) * rs * g.x + bb.x);
  o.y = f2bf((v.y - mu) * rs * g.y + bb.y);
  o.z = f2bf((v.z - mu) * rs * g.z + bb.z);
  o.w = f2bf((v.w - mu) * rs * g.w + bb.w);
  *(ushort4*)(xn + token * 256 + lane * 4) = o;
}

// ------------------------------------------------- QKV projections (MFMA)
// z: 0 = q (stream 0, Wq, scaled, C^T out)
// z: 1 = kv_e, 2 = kv_l: xf loaded ONCE feeds Wk (A-form, C^T) AND Wv
// (B-form, 32x32-fragment vT3 out).  No LDS; xf double-buffered.
// ROUND 14: 64 tokens/block (grid 256 x 2 x 3 = 1536 blocks = 6/CU).
__global__ __launch_bounds__(256) void proj_kernel(
    const ushort* __restrict__ xn,
    const ushort* __restrict__ wq, const ushort* __restrict__ wk,
    const ushort* __restrict__ wv,
    const float* __restrict__ bq, const float* __restrict__ bk,
    const float* __restrict__ bv,
    ushort* __restrict__ qb, ushort* __restrict__ keb, ushort* __restrict__ vTe,
    ushort* __restrict__ klb, ushort* __restrict__ vTl) {
  int z = blockIdx.z;
  int tid = threadIdx.x;
  int w = tid >> 6, lane = tid & 63;
  int n = lane & 15, quad = lane >> 4;
  int cbase = blockIdx.y * 128 + w * 32;
  int b = (blockIdx.x * 64) >> 11;
  int r0 = (blockIdx.x * 64) & 2047;

  if (z == 0) {
    const ushort* xbase = xn + ((size_t)b * 6144 + r0) * 256;
    short8 wf[2][8];
#pragma unroll
    for (int ct = 0; ct < 2; ++ct)
#pragma unroll
      for (int kc = 0; kc < 8; ++kc)
        wf[ct][kc] = *(const short8*)(wq + (size_t)(cbase + ct * 16 + n) * 256 + kc * 32 + quad * 8);
    float4 bt[2];
    bt[0] = *(const float4*)(bq + cbase + quad * 4);
    bt[1] = *(const float4*)(bq + cbase + 16 + quad * 4);

    short8 xfA[8], xfB[8];
#pragma unroll
    for (int kc = 0; kc < 8; ++kc)
      xfA[kc] = *(const short8*)(xbase + (size_t)n * 256 + kc * 32 + quad * 8);

#pragma unroll
    for (int tt = 0; tt < 4; ++tt) {
      const short8* cur = (tt & 1) ? xfB : xfA;
      short8* nxt = (tt & 1) ? xfA : xfB;
      if (tt < 3) {
#pragma unroll
        for (int kc = 0; kc < 8; ++kc)
          nxt[kc] = *(const short8*)(xbase + (size_t)((tt + 1) * 16 + n) * 256 + kc * 32 + quad * 8);
      }
      f32x4 acc[2] = {{0.f, 0.f, 0.f, 0.f}, {0.f, 0.f, 0.f, 0.f}};
#pragma unroll
      for (int ct = 0; ct < 2; ++ct)
#pragma unroll
        for (int kc = 0; kc < 8; ++kc)
          acc[ct] = __builtin_amdgcn_mfma_f32_16x16x32_bf16(wf[ct][kc], cur[kc], acc[ct], 0, 0, 0);
      int n2 = r0 + tt * 16 + n;
#pragma unroll
      for (int ct = 0; ct < 2; ++ct) {
        int c = cbase + ct * 16 + quad * 4;
        int h = c >> 5, d = c & 31;
        float* bp = (float*)&bt[ct];
        ushort4 st;
        st.x = f2bf((acc[ct][0] + bp[0]) * QSCALE);
        st.y = f2bf((acc[ct][1] + bp[1]) * QSCALE);
        st.z = f2bf((acc[ct][2] + bp[2]) * QSCALE);
        st.w = f2bf((acc[ct][3] + bp[3]) * QSCALE);
        *(ushort4*)(qb + (((size_t)(b * 8 + h) * 2048) + n2) * 32 + d) = st;
      }
    }
  } else {
    int s = z;
    ushort* kout = (z == 1) ? keb : klb;
    ushort* vout = (z == 1) ? vTe : vTl;
    const ushort* xbase = xn + ((size_t)b * 6144 + s * 2048 + r0) * 256;
    short8 wfk[2][8], wfv[2][8];
#pragma unroll
    for (int ct = 0; ct < 2; ++ct)
#pragma unroll
      for (int kc = 0; kc < 8; ++kc) {
        wfk[ct][kc] = *(const short8*)(wk + (size_t)(cbase + ct * 16 + n) * 256 + kc * 32 + quad * 8);
        wfv[ct][kc] = *(const short8*)(wv + (size_t)(cbase + ct * 16 + n) * 256 + kc * 32 + quad * 8);
      }
    float4 btk[2];
    btk[0] = *(const float4*)(bk + cbase + quad * 4);
    btk[1] = *(const float4*)(bk + cbase + 16 + quad * 4);
    float bsv[2] = {bv[cbase + n], bv[cbase + 16 + n]};

    short8 xfA[8], xfB[8];
#pragma unroll
    for (int kc = 0; kc < 8; ++kc)
      xfA[kc] = *(const short8*)(xbase + (size_t)n * 256 + kc * 32 + quad * 8);

#pragma unroll
    for (int tt = 0; tt < 4; ++tt) {
      const short8* cur = (tt & 1) ? xfB : xfA;
      short8* nxt = (tt & 1) ? xfA : xfB;
      if (tt < 3) {
#pragma unroll
        for (int kc = 0; kc < 8; ++kc)
          nxt[kc] = *(const short8*)(xbase + (size_t)((tt + 1) * 16 + n) * 256 + kc * 32 + quad * 8);
      }
      f32x4 ack[2] = {{0.f, 0.f, 0.f, 0.f}, {0.f, 0.f, 0.f, 0.f}};
      f32x4 acv[2] = {{0.f, 0.f, 0.f, 0.f}, {0.f, 0.f, 0.f, 0.f}};
#pragma unroll
      for (int ct = 0; ct < 2; ++ct)
#pragma unroll
        for (int kc = 0; kc < 8; ++kc) {
          ack[ct] = __builtin_amdgcn_mfma_f32_16x16x32_bf16(wfk[ct][kc], cur[kc], ack[ct], 0, 0, 0);
          acv[ct] = __builtin_amdgcn_mfma_f32_16x16x32_bf16(cur[kc], wfv[ct][kc], acv[ct], 0, 0, 0);
        }
      // store k: C^T row-major [bh][2048][32] (lane: token n2, cols quad*4+r)
      int n2 = r0 + tt * 16 + n;
#pragma unroll
      for (int ct = 0; ct < 2; ++ct) {
        int c = cbase + ct * 16 + quad * 4;
        int h = c >> 5, d = c & 31;
        float* bp = (float*)&btk[ct];
        ushort4 st;
        st.x = f2bf(ack[ct][0] + bp[0]);
        st.y = f2bf(ack[ct][1] + bp[1]);
        st.z = f2bf(ack[ct][2] + bp[2]);
        st.w = f2bf(ack[ct][3] + bp[3]);
        *(ushort4*)(kout + (((size_t)(b * 8 + h) * 2048) + n2) * 32 + d) = st;
      }
      // store v: 32x32 B-fragment layout vT3[bh][ktile][u][lane2][8].
      // acv reg r is token tq+r; kappa = quad*4+r -> hi2=quad&1,
      // i = r + 4*(quad>>1)  (8*(quad>>1)+4*(quad&1) == 4*quad)
      int tq = r0 + tt * 16 + quad * 4;
      int ktile = tq >> 5;
      int u = (tq >> 4) & 1;
      int i0 = 4 * (quad >> 1);
      int hi2 = quad & 1;
#pragma unroll
      for (int ct = 0; ct < 2; ++ct) {
        int c = cbase + ct * 16 + n;
        int h = c >> 5;
        int d = ct * 16 + n;          // c & 31 (cbase is 32-aligned)
        int lane2 = d + 32 * hi2;
        ushort4 st;
        st.x = f2bf(acv[ct][0] + bsv[ct]);
        st.y = f2bf(acv[ct][1] + bsv[ct]);
        st.z = f2bf(acv[ct][2] + bsv[ct]);
        st.w = f2bf(acv[ct][3] + bsv[ct]);
        *(ushort4*)(vout + (size_t)(b * 8 + h) * 65536
                    + ktile * 1024 + u * 512 + lane2 * 8 + i0) = st;
      }
    }
  }
}

// ------------------------------------------------ flash attention bf16 MFMA
// (byte-identical to r13 -- control for this round's attribution)
__global__ __launch_bounds__(256, 3) void attn_kernel(
    const ushort* __restrict__ q,
    const ushort* __restrict__ ke, const ushort* __restrict__ vTe,
    const ushort* __restrict__ kl, const ushort* __restrict__ vTl,
    ushort* __restrict__ osum_e, ushort* __restrict__ osum_l) {
  int tid = threadIdx.x;
  int w = tid >> 6, lane = tid & 63;
  int l31 = lane & 31, hi = lane >> 5;

  int L = blockIdx.y * 8 + blockIdx.x;
  int xcd = L & 7, idx = L >> 3;          // idx in [0,256)
  int bh = (idx >> 5) * 8 + xcd;
  int rem = idx & 31;
  int s = rem >> 4;                        // stream 0=e, 1=l
  int q0 = (rem & 15) * 128;
  int qbase = q0 + w * 32;

  const ushort* K  = (s == 0 ? ke : kl) + (size_t)bh * 65536;
  const ushort* VT = (s == 0 ? vTe : vTl) + (size_t)bh * 65536;
  ushort* osum = (s == 0) ? osum_e : osum_l;

  short8 qf[2];
#pragma unroll
  for (int sl = 0; sl < 2; ++sl)
    qf[sl] = *(const short8*)(q + ((size_t)bh * 2048 + qbase + l31) * 32 + sl * 16 + hi * 8);

  f32x16 zero16;
#pragma unroll
  for (int r = 0; r < 16; ++r) zero16[r] = 0.f;
  f32x16 oa0 = zero16, oa1 = zero16;   // two independent PV accumulators
  float lsum = 0.f;

  auto loadKV = [&](short8* kf, short8* vf, int jt) {
    const ushort* kb = K + (size_t)jt * 2048;   // 64 keys * 32 d
#pragma unroll
    for (int kt = 0; kt < 2; ++kt)
#pragma unroll
      for (int sl = 0; sl < 2; ++sl)
        kf[kt * 2 + sl] = *(const short8*)(kb + (kt * 32 + l31) * 32 + sl * 16 + hi * 8);
    const ushort* vb = VT + (size_t)jt * 2048 + lane * 8;
#pragma unroll
    for (int m = 0; m < 4; ++m)                 // m = kt*2+u
      vf[m] = *(const short8*)(vb + m * 512);
  };

  // finish one kt-half: exp -> lsum tree -> pack -> PV (2 MFMAs)
  auto finish = [&](const f32x16& sacc, const short8* vf2) {
    float p[16];
#pragma unroll
    for (int r = 0; r < 16; ++r) p[r] = __builtin_amdgcn_exp2f(sacc[r]);
    float t0 = (p[0] + p[1]) + (p[2] + p[3]);
    float t1 = (p[4] + p[5]) + (p[6] + p[7]);
    float t2 = (p[8] + p[9]) + (p[10] + p[11]);
    float t3 = (p[12] + p[13]) + (p[14] + p[15]);
    lsum += (t0 + t1) + (t2 + t3);
    short8 pa0, pa1;
    {
      union { uint4 uu; short8 s8; } cv;
      cv.uu.x = pk2bf(p[0], p[1]);
      cv.uu.y = pk2bf(p[2], p[3]);
      cv.uu.z = pk2bf(p[4], p[5]);
      cv.uu.w = pk2bf(p[6], p[7]);
      pa0 = cv.s8;
    }
    {
      union { uint4 uu; short8 s8; } cv;
      cv.uu.x = pk2bf(p[8], p[9]);
      cv.uu.y = pk2bf(p[10], p[11]);
      cv.uu.z = pk2bf(p[12], p[13]);
      cv.uu.w = pk2bf(p[14], p[15]);
      pa1 = cv.s8;
    }
    oa0 = __builtin_amdgcn_mfma_f32_32x32x16_bf16(pa0, vf2[0], oa0, 0, 0, 0);
    oa1 = __builtin_amdgcn_mfma_f32_32x32x16_bf16(pa1, vf2[1], oa1, 0, 0, 0);
  };

  auto compute = [&](const short8* kf, const short8* vf) {
    f32x16 sacc0 = __builtin_amdgcn_mfma_f32_32x32x16_bf16(kf[0], qf[0], zero16, 0, 0, 0);
    sacc0 = __builtin_amdgcn_mfma_f32_32x32x16_bf16(kf[1], qf[1], sacc0, 0, 0, 0);
    f32x16 sacc1 = __builtin_amdgcn_mfma_f32_32x32x16_bf16(kf[2], qf[0], zero16, 0, 0, 0);
    sacc1 = __builtin_amdgcn_mfma_f32_32x32x16_bf16(kf[3], qf[1], sacc1, 0, 0, 0);
    finish(sacc0, vf + 0);
    finish(sacc1, vf + 2);
  };

  short8 kfA[4], kfB[4], vfA[4], vfB[4];
  loadKV(kfA, vfA, 0);
  for (int jt = 0; jt < 32; jt += 2) {
    loadKV(kfB, vfB, jt + 1);   // in flight during compute(A)
    compute(kfA, vfA);
    if (jt + 2 < 32) loadKV(kfA, vfA, jt + 2);
    compute(kfB, vfB);
  }

  // denominator: lanes l and l^32 hold complementary key-halves of q=l31
  lsum += __shfl_xor(lsum, 32, 64);
  float inv = __builtin_amdgcn_rcpf(lsum);

  int b = bh >> 3, h = bh & 7;
#pragma unroll
  for (int r = 0; r < 16; ++r) {
    int qr = (r & 3) + 8 * (r >> 2) + 4 * hi;
    float invr = __shfl(inv, qr, 64);
    float v = (oa0[r] + oa1[r]) * invr;
    size_t row = (size_t)b * 2048 + qbase + qr;
    osum[row * 256 + h * 32 + l31] = f2bf(v);
  }
}

// ------------------------------------------- output projection (MFMA, C^T)
// out[t][c] = sum_k (ose[t][k]+osl[t][k])*Wo[c][k] + 2*bo[c]: both streams
// accumulated into the same MFMA C (K=512 total).
// ROUND 14: 32-row blocks (grid 512 x 2 = 1024 blocks = 4/CU).
__global__ __launch_bounds__(256) void outproj_kernel(
    const ushort* __restrict__ ose, const ushort* __restrict__ osl,
    const ushort* __restrict__ wo,
    const float* __restrict__ bo, float* __restrict__ out) {
  int tid = threadIdx.x;
  int w = tid >> 6, lane = tid & 63;
  int n = lane & 15, quad = lane >> 4;
  int cbase = blockIdx.y * 128 + w * 32;

  short8 wfrag[2][8];
#pragma unroll
  for (int ct = 0; ct < 2; ++ct)
#pragma unroll
    for (int kc = 0; kc < 8; ++kc)
      wfrag[ct][kc] = *(const short8*)(wo + (size_t)(cbase + ct * 16 + n) * 256 + kc * 32 + quad * 8);
  float4 bt[2];
  bt[0] = *(const float4*)(bo + cbase + quad * 4);
  bt[1] = *(const float4*)(bo + cbase + 16 + quad * 4);

  const ushort* ae = ose + (size_t)(blockIdx.x * 32) * 256;
  const ushort* al = osl + (size_t)(blockIdx.x * 32) * 256;

#pragma unroll
  for (int tt = 0; tt < 2; ++tt) {
    short8 xe[8], xl[8];
#pragma unroll
    for (int kc = 0; kc < 8; ++kc)
      xe[kc] = *(const short8*)(ae + (size_t)(tt * 16 + n) * 256 + kc * 32 + quad * 8);
#pragma unroll
    for (int kc = 0; kc < 8; ++kc)
      xl[kc] = *(const short8*)(al + (size_t)(tt * 16 + n) * 256 + kc * 32 + quad * 8);

    int tok = blockIdx.x * 32 + tt * 16 + n;
    f32x4 acc[2] = {{0.f, 0.f, 0.f, 0.f}, {0.f, 0.f, 0.f, 0.f}};
#pragma unroll
    for (int ct = 0; ct < 2; ++ct)
#pragma unroll
      for (int kc = 0; kc < 8; ++kc)
        acc[ct] = __builtin_amdgcn_mfma_f32_16x16x32_bf16(wfrag[ct][kc], xe[kc], acc[ct], 0, 0, 0);
#pragma unroll
    for (int ct = 0; ct < 2; ++ct)
#pragma unroll
      for (int kc = 0; kc < 8; ++kc)
        acc[ct] = __builtin_amdgcn_mfma_f32_16x16x32_bf16(wfrag[ct][kc], xl[kc], acc[ct], 0, 0, 0);
#pragma unroll
    for (int ct = 0; ct < 2; ++ct) {
      int c = cbase + ct * 16 + quad * 4;
      float* bp = (float*)&bt[ct];
      float4 st;
      st.x = acc[ct][0] + 2.0f * bp[0];
      st.y = acc[ct][1] + 2.0f * bp[1];
      st.z = acc[ct][2] + 2.0f * bp[2];
      st.w = acc[ct][3] + 2.0f * bp[3];
      *(float4*)(out + (size_t)tok * 256 + c) = st;
    }
  }
}

extern "C" void kernel_launch(void* const* d_in, const int* in_sizes, int n_in,
                              void* d_out, int out_size, void* d_ws, size_t ws_size,
                              hipStream_t stream) {
  const float* x   = (const float*)d_in[0];
  const float* lng = (const float*)d_in[1];
  const float* lnb = (const float*)d_in[2];
  const float* Wq  = (const float*)d_in[3];
  const float* bq  = (const float*)d_in[4];
  const float* Wk  = (const float*)d_in[5];
  const float* bk  = (const float*)d_in[6];
  const float* Wv  = (const float*)d_in[7];
  const float* bv  = (const float*)d_in[8];
  const float* Wo  = (const float*)d_in[9];
  const float* bo  = (const float*)d_in[10];
  float* out = (float*)d_out;

  ushort* ws = (ushort*)d_ws;
  const size_t XN  = (size_t)49152 * 256;      // 12,582,912
  const size_t QKV = (size_t)64 * 2048 * 32;   //  4,194,304
  ushort* xn     = ws;
  ushort* wbf    = xn + XN;          // [Wq|Wk|Wv|Wo] x 65536
  ushort* qb     = wbf + 4 * 65536;
  ushort* keb    = qb  + QKV;
  ushort* vTe    = keb + QKV;
  ushort* klb    = vTe + QKV;
  ushort* vTl    = klb + QKV;
  ushort* osum_e = vTl + QKV;
  ushort* osum_l = xn;               // alias: xn is dead after proj_kernel

  hipLaunchKernelGGL(ln_wcast_kernel, dim3(12544), dim3(256), 0, stream,
                     x, lng, lnb, Wq, Wk, Wv, Wo, xn, wbf);
  hipLaunchKernelGGL(proj_kernel, dim3(256, 2, 3), dim3(256), 0, stream,
                     xn, wbf, wbf + 65536, wbf + 131072, bq, bk, bv,
                     qb, keb, vTe, klb, vTl);
  hipLaunchKernelGGL(attn_kernel, dim3(8, 256), dim3(256), 0, stream,
                     qb, keb, vTe, klb, vTl, osum_e, osum_l);
  hipLaunchKernelGGL(outproj_kernel, dim3(512, 2), dim3(256), 0, stream,
                     osum_e, osum_l, wbf + 196608, bo, out);
}

// Round 15
// 267.366 us; speedup vs baseline: 1.0573x; 1.0573x over previous
//
#include <hip/hip_runtime.h>
#include <hip/hip_bf16.h>
#include <math.h>

#define LN_EPS 1e-5f
// dim^-0.5 * log2(e): folded into q so softmax is exp2(s) with no muls
#define QSCALE 0.09016844005556021f

typedef __attribute__((ext_vector_type(8))) short short8;
typedef __attribute__((ext_vector_type(4))) short short4v;
typedef __attribute__((ext_vector_type(4))) float f32x4;
typedef __attribute__((ext_vector_type(16))) float f32x16;

__device__ inline ushort f2bf(float f) {
  __hip_bfloat16 h = __float2bfloat16(f);
  return *reinterpret_cast<ushort*>(&h);
}

// pack two positive fp32 into bf16 pair (lo=a, hi=b): +0x8000 then v_perm.
// (hardware-verified; kept for proj epilogues)
__device__ inline uint pk2bf(float a, float b) {
  uint ua = __float_as_uint(a) + 0x8000u;
  uint ub = __float_as_uint(b) + 0x8000u;
  return __builtin_amdgcn_perm(ub, ua, 0x07060302u);
}

// Shapes (fixed): b=8, n=2048/stream, 3 streams, dim=256, heads=8, d=32.
// xn (bf16): [8*6144][256].  q/k (bf16): [bh][2048][32] row-major -- these
//   double as 32x32x16 MFMA A/B fragment sources (row=lane&31, k=hi*8+i).
// vT3 (bf16, 32x32 B-FRAGMENT layout): [bh][64 ktile32][2 u][64 lane][8]:
//   elem = V[key = ktile*32 + 16u + (i&3) + 8*(i>>2) + 4*(lane>>5)]
//            [d = lane&31]  (key perm == 32x32 MFMA C-row pattern, so attn's
//   P-register file feeds PV's A operand with NO data movement).
// osum_e / osum_l (bf16): [b*2048][256] (osum_l aliases dead xn region).
// ROUND 15: r14's smaller blocks REGRESSED (+11.5us: weight-prologue
// amortization dominates proj/outproj, not block supply) -- grids reverted
// to r13.  attn: replace 3-op pk2bf with plain f2bf scalar casts so the
// compiler fuses pairs into v_cvt_pk_bf16_f32 (m240: scalar casts fuse;
// hand-written packs block the fusion).  Pack cost 24->8 ops per finish.

// ---------------------- fused: LN-normalize -> bf16  +  weight cast -> bf16
__global__ __launch_bounds__(256) void ln_wcast_kernel(
    const float* __restrict__ x, const float* __restrict__ lng,
    const float* __restrict__ lnb,
    const float* __restrict__ Wq, const float* __restrict__ Wk,
    const float* __restrict__ Wv, const float* __restrict__ Wo,
    ushort* __restrict__ xn, ushort* __restrict__ wbf) {
  if (blockIdx.x < 256) {
    int t = blockIdx.x * 256 + threadIdx.x;
    int e0 = t * 4;
    int m = e0 >> 16, off = e0 & 65535;
    const float* src = (m == 0) ? Wq : (m == 1) ? Wk : (m == 2) ? Wv : Wo;
    float4 v = *(const float4*)(src + off);
    ushort4 o;
    o.x = f2bf(v.x); o.y = f2bf(v.y); o.z = f2bf(v.z); o.w = f2bf(v.w);
    *(ushort4*)(wbf + m * 65536 + off) = o;
    return;
  }
  int w = threadIdx.x >> 6;
  int lane = threadIdx.x & 63;
  size_t token = (size_t)(blockIdx.x - 256) * 4 + w;
  float4 v = *(const float4*)(x + token * 256 + lane * 4);
  float s  = v.x + v.y + v.z + v.w;
  float s2 = v.x * v.x + v.y * v.y + v.z * v.z + v.w * v.w;
#pragma unroll
  for (int off = 32; off >= 1; off >>= 1) {
    s  += __shfl_xor(s, off, 64);
    s2 += __shfl_xor(s2, off, 64);
  }
  float mu  = s * (1.0f / 256.0f);
  float var = s2 * (1.0f / 256.0f) - mu * mu;
  float rs  = rsqrtf(var + LN_EPS);
  float4 g = *(const float4*)(lng + lane * 4);
  float4 bb = *(const float4*)(lnb + lane * 4);
  ushort4 o;
  o.x = f2bf((v.x - mu) * rs * g.x + bb.x);
  o.y = f2bf((v.y - mu) * rs * g.y + bb.y);
  o.z = f2bf((v.z - mu) * rs * g.z + bb.z);
  o.w = f2bf((v.w - mu) * rs * g.w + bb.w);
  *(ushort4*)(xn + token * 256 + lane * 4) = o;
}

// ------------------------------------------------- QKV projections (MFMA)
// z: 0 = q (stream 0, Wq, scaled, C^T out)
// z: 1 = kv_e, 2 = kv_l: xf loaded ONCE feeds Wk (A-form, C^T) AND Wv
// (B-form, 32x32-fragment vT3 out).  No LDS; xf double-buffered.
// 128 tokens/block (grid 128 x 2 x 3 = 768): r13 config (r14's 64/block
// regressed -- weight prologue amortization wins over supply).
__global__ __launch_bounds__(256) void proj_kernel(
    const ushort* __restrict__ xn,
    const ushort* __restrict__ wq, const ushort* __restrict__ wk,
    const ushort* __restrict__ wv,
    const float* __restrict__ bq, const float* __restrict__ bk,
    const float* __restrict__ bv,
    ushort* __restrict__ qb, ushort* __restrict__ keb, ushort* __restrict__ vTe,
    ushort* __restrict__ klb, ushort* __restrict__ vTl) {
  int z = blockIdx.z;
  int tid = threadIdx.x;
  int w = tid >> 6, lane = tid & 63;
  int n = lane & 15, quad = lane >> 4;
  int cbase = blockIdx.y * 128 + w * 32;
  int b = (blockIdx.x * 128) >> 11;
  int r0 = (blockIdx.x * 128) & 2047;

  if (z == 0) {
    const ushort* xbase = xn + ((size_t)b * 6144 + r0) * 256;
    short8 wf[2][8];
#pragma unroll
    for (int ct = 0; ct < 2; ++ct)
#pragma unroll
      for (int kc = 0; kc < 8; ++kc)
        wf[ct][kc] = *(const short8*)(wq + (size_t)(cbase + ct * 16 + n) * 256 + kc * 32 + quad * 8);
    float4 bt[2];
    bt[0] = *(const float4*)(bq + cbase + quad * 4);
    bt[1] = *(const float4*)(bq + cbase + 16 + quad * 4);

    short8 xfA[8], xfB[8];
#pragma unroll
    for (int kc = 0; kc < 8; ++kc)
      xfA[kc] = *(const short8*)(xbase + (size_t)n * 256 + kc * 32 + quad * 8);

#pragma unroll
    for (int tt = 0; tt < 8; ++tt) {
      const short8* cur = (tt & 1) ? xfB : xfA;
      short8* nxt = (tt & 1) ? xfA : xfB;
      if (tt < 7) {
#pragma unroll
        for (int kc = 0; kc < 8; ++kc)
          nxt[kc] = *(const short8*)(xbase + (size_t)((tt + 1) * 16 + n) * 256 + kc * 32 + quad * 8);
      }
      f32x4 acc[2] = {{0.f, 0.f, 0.f, 0.f}, {0.f, 0.f, 0.f, 0.f}};
#pragma unroll
      for (int ct = 0; ct < 2; ++ct)
#pragma unroll
        for (int kc = 0; kc < 8; ++kc)
          acc[ct] = __builtin_amdgcn_mfma_f32_16x16x32_bf16(wf[ct][kc], cur[kc], acc[ct], 0, 0, 0);
      int n2 = r0 + tt * 16 + n;
#pragma unroll
      for (int ct = 0; ct < 2; ++ct) {
        int c = cbase + ct * 16 + quad * 4;
        int h = c >> 5, d = c & 31;
        float* bp = (float*)&bt[ct];
        ushort4 st;
        st.x = f2bf((acc[ct][0] + bp[0]) * QSCALE);
        st.y = f2bf((acc[ct][1] + bp[1]) * QSCALE);
        st.z = f2bf((acc[ct][2] + bp[2]) * QSCALE);
        st.w = f2bf((acc[ct][3] + bp[3]) * QSCALE);
        *(ushort4*)(qb + (((size_t)(b * 8 + h) * 2048) + n2) * 32 + d) = st;
      }
    }
  } else {
    int s = z;
    ushort* kout = (z == 1) ? keb : klb;
    ushort* vout = (z == 1) ? vTe : vTl;
    const ushort* xbase = xn + ((size_t)b * 6144 + s * 2048 + r0) * 256;
    short8 wfk[2][8], wfv[2][8];
#pragma unroll
    for (int ct = 0; ct < 2; ++ct)
#pragma unroll
      for (int kc = 0; kc < 8; ++kc) {
        wfk[ct][kc] = *(const short8*)(wk + (size_t)(cbase + ct * 16 + n) * 256 + kc * 32 + quad * 8);
        wfv[ct][kc] = *(const short8*)(wv + (size_t)(cbase + ct * 16 + n) * 256 + kc * 32 + quad * 8);
      }
    float4 btk[2];
    btk[0] = *(const float4*)(bk + cbase + quad * 4);
    btk[1] = *(const float4*)(bk + cbase + 16 + quad * 4);
    float bsv[2] = {bv[cbase + n], bv[cbase + 16 + n]};

    short8 xfA[8], xfB[8];
#pragma unroll
    for (int kc = 0; kc < 8; ++kc)
      xfA[kc] = *(const short8*)(xbase + (size_t)n * 256 + kc * 32 + quad * 8);

#pragma unroll
    for (int tt = 0; tt < 8; ++tt) {
      const short8* cur = (tt & 1) ? xfB : xfA;
      short8* nxt = (tt & 1) ? xfA : xfB;
      if (tt < 7) {
#pragma unroll
        for (int kc = 0; kc < 8; ++kc)
          nxt[kc] = *(const short8*)(xbase + (size_t)((tt + 1) * 16 + n) * 256 + kc * 32 + quad * 8);
      }
      f32x4 ack[2] = {{0.f, 0.f, 0.f, 0.f}, {0.f, 0.f, 0.f, 0.f}};
      f32x4 acv[2] = {{0.f, 0.f, 0.f, 0.f}, {0.f, 0.f, 0.f, 0.f}};
#pragma unroll
      for (int ct = 0; ct < 2; ++ct)
#pragma unroll
        for (int kc = 0; kc < 8; ++kc) {
          ack[ct] = __builtin_amdgcn_mfma_f32_16x16x32_bf16(wfk[ct][kc], cur[kc], ack[ct], 0, 0, 0);
          acv[ct] = __builtin_amdgcn_mfma_f32_16x16x32_bf16(cur[kc], wfv[ct][kc], acv[ct], 0, 0, 0);
        }
      // store k: C^T row-major [bh][2048][32] (lane: token n2, cols quad*4+r)
      int n2 = r0 + tt * 16 + n;
#pragma unroll
      for (int ct = 0; ct < 2; ++ct) {
        int c = cbase + ct * 16 + quad * 4;
        int h = c >> 5, d = c & 31;
        float* bp = (float*)&btk[ct];
        ushort4 st;
        st.x = f2bf(ack[ct][0] + bp[0]);
        st.y = f2bf(ack[ct][1] + bp[1]);
        st.z = f2bf(ack[ct][2] + bp[2]);
        st.w = f2bf(ack[ct][3] + bp[3]);
        *(ushort4*)(kout + (((size_t)(b * 8 + h) * 2048) + n2) * 32 + d) = st;
      }
      // store v: 32x32 B-fragment layout vT3[bh][ktile][u][lane2][8].
      // acv reg r is token tq+r; kappa = quad*4+r -> hi2=quad&1,
      // i = r + 4*(quad>>1)  (8*(quad>>1)+4*(quad&1) == 4*quad)
      int tq = r0 + tt * 16 + quad * 4;
      int ktile = tq >> 5;
      int u = (tq >> 4) & 1;
      int i0 = 4 * (quad >> 1);
      int hi2 = quad & 1;
#pragma unroll
      for (int ct = 0; ct < 2; ++ct) {
        int c = cbase + ct * 16 + n;
        int h = c >> 5;
        int d = ct * 16 + n;          // c & 31 (cbase is 32-aligned)
        int lane2 = d + 32 * hi2;
        ushort4 st;
        st.x = f2bf(acv[ct][0] + bsv[ct]);
        st.y = f2bf(acv[ct][1] + bsv[ct]);
        st.z = f2bf(acv[ct][2] + bsv[ct]);
        st.w = f2bf(acv[ct][3] + bsv[ct]);
        *(ushort4*)(vout + (size_t)(b * 8 + h) * 65536
                    + ktile * 1024 + u * 512 + lane2 * 8 + i0) = st;
      }
    }
  }
}

// ------------------------------------------------ flash attention bf16 MFMA
// 32x32x16 structure; tree-sum denominator; two PV accumulators; fence-free
// hoisted QK (r13).  ROUND 15: P->bf16 pack via plain f2bf scalar casts --
// compiler fuses pairs into v_cvt_pk_bf16_f32 (m240), replacing the 3-op
// pk2bf per pair.  Pack VALU 24->8 ops per finish (~27% of jt VALU volume).
__global__ __launch_bounds__(256, 3) void attn_kernel(
    const ushort* __restrict__ q,
    const ushort* __restrict__ ke, const ushort* __restrict__ vTe,
    const ushort* __restrict__ kl, const ushort* __restrict__ vTl,
    ushort* __restrict__ osum_e, ushort* __restrict__ osum_l) {
  int tid = threadIdx.x;
  int w = tid >> 6, lane = tid & 63;
  int l31 = lane & 31, hi = lane >> 5;

  int L = blockIdx.y * 8 + blockIdx.x;
  int xcd = L & 7, idx = L >> 3;          // idx in [0,256)
  int bh = (idx >> 5) * 8 + xcd;
  int rem = idx & 31;
  int s = rem >> 4;                        // stream 0=e, 1=l
  int q0 = (rem & 15) * 128;
  int qbase = q0 + w * 32;

  const ushort* K  = (s == 0 ? ke : kl) + (size_t)bh * 65536;
  const ushort* VT = (s == 0 ? vTe : vTl) + (size_t)bh * 65536;
  ushort* osum = (s == 0) ? osum_e : osum_l;

  short8 qf[2];
#pragma unroll
  for (int sl = 0; sl < 2; ++sl)
    qf[sl] = *(const short8*)(q + ((size_t)bh * 2048 + qbase + l31) * 32 + sl * 16 + hi * 8);

  f32x16 zero16;
#pragma unroll
  for (int r = 0; r < 16; ++r) zero16[r] = 0.f;
  f32x16 oa0 = zero16, oa1 = zero16;   // two independent PV accumulators
  float lsum = 0.f;

  auto loadKV = [&](short8* kf, short8* vf, int jt) {
    const ushort* kb = K + (size_t)jt * 2048;   // 64 keys * 32 d
#pragma unroll
    for (int kt = 0; kt < 2; ++kt)
#pragma unroll
      for (int sl = 0; sl < 2; ++sl)
        kf[kt * 2 + sl] = *(const short8*)(kb + (kt * 32 + l31) * 32 + sl * 16 + hi * 8);
    const ushort* vb = VT + (size_t)jt * 2048 + lane * 8;
#pragma unroll
    for (int m = 0; m < 4; ++m)                 // m = kt*2+u
      vf[m] = *(const short8*)(vb + m * 512);
  };

  // finish one kt-half: exp -> lsum tree -> pack (scalar f2bf: compiler
  // fuses to v_cvt_pk_bf16_f32) -> PV (2 MFMAs)
  auto finish = [&](const f32x16& sacc, const short8* vf2) {
    float p[16];
#pragma unroll
    for (int r = 0; r < 16; ++r) p[r] = __builtin_amdgcn_exp2f(sacc[r]);
    float t0 = (p[0] + p[1]) + (p[2] + p[3]);
    float t1 = (p[4] + p[5]) + (p[6] + p[7]);
    float t2 = (p[8] + p[9]) + (p[10] + p[11]);
    float t3 = (p[12] + p[13]) + (p[14] + p[15]);
    lsum += (t0 + t1) + (t2 + t3);
    short8 pa0, pa1;
    {
      union { ushort u[8]; short8 s8; } cv;
#pragma unroll
      for (int j = 0; j < 8; ++j) cv.u[j] = f2bf(p[j]);
      pa0 = cv.s8;
    }
    {
      union { ushort u[8]; short8 s8; } cv;
#pragma unroll
      for (int j = 0; j < 8; ++j) cv.u[j] = f2bf(p[8 + j]);
      pa1 = cv.s8;
    }
    oa0 = __builtin_amdgcn_mfma_f32_32x32x16_bf16(pa0, vf2[0], oa0, 0, 0, 0);
    oa1 = __builtin_amdgcn_mfma_f32_32x32x16_bf16(pa1, vf2[1], oa1, 0, 0, 0);
  };

  auto compute = [&](const short8* kf, const short8* vf) {
    f32x16 sacc0 = __builtin_amdgcn_mfma_f32_32x32x16_bf16(kf[0], qf[0], zero16, 0, 0, 0);
    sacc0 = __builtin_amdgcn_mfma_f32_32x32x16_bf16(kf[1], qf[1], sacc0, 0, 0, 0);
    f32x16 sacc1 = __builtin_amdgcn_mfma_f32_32x32x16_bf16(kf[2], qf[0], zero16, 0, 0, 0);
    sacc1 = __builtin_amdgcn_mfma_f32_32x32x16_bf16(kf[3], qf[1], sacc1, 0, 0, 0);
    finish(sacc0, vf + 0);
    finish(sacc1, vf + 2);
  };

  short8 kfA[4], kfB[4], vfA[4], vfB[4];
  loadKV(kfA, vfA, 0);
  for (int jt = 0; jt < 32; jt += 2) {
    loadKV(kfB, vfB, jt + 1);   // in flight during compute(A)
    compute(kfA, vfA);
    if (jt + 2 < 32) loadKV(kfA, vfA, jt + 2);
    compute(kfB, vfB);
  }

  // denominator: lanes l and l^32 hold complementary key-halves of q=l31
  lsum += __shfl_xor(lsum, 32, 64);
  float inv = __builtin_amdgcn_rcpf(lsum);

  int b = bh >> 3, h = bh & 7;
#pragma unroll
  for (int r = 0; r < 16; ++r) {
    int qr = (r & 3) + 8 * (r >> 2) + 4 * hi;
    float invr = __shfl(inv, qr, 64);
    float v = (oa0[r] + oa1[r]) * invr;
    size_t row = (size_t)b * 2048 + qbase + qr;
    osum[row * 256 + h * 32 + l31] = f2bf(v);
  }
}

// ------------------------------------------- output projection (MFMA, C^T)
// out[t][c] = sum_k (ose[t][k]+osl[t][k])*Wo[c][k] + 2*bo[c]: both streams
// accumulated into the same MFMA C (K=512).  64-row blocks (grid 512, r13).
__global__ __launch_bounds__(256) void outproj_kernel(
    const ushort* __restrict__ ose, const ushort* __restrict__ osl,
    const ushort* __restrict__ wo,
    const float* __restrict__ bo, float* __restrict__ out) {
  int tid = threadIdx.x;
  int w = tid >> 6, lane = tid & 63;
  int n = lane & 15, quad = lane >> 4;
  int cbase = blockIdx.y * 128 + w * 32;

  short8 wfrag[2][8];
#pragma unroll
  for (int ct = 0; ct < 2; ++ct)
#pragma unroll
    for (int kc = 0; kc < 8; ++kc)
      wfrag[ct][kc] = *(const short8*)(wo + (size_t)(cbase + ct * 16 + n) * 256 + kc * 32 + quad * 8);
  float4 bt[2];
  bt[0] = *(const float4*)(bo + cbase + quad * 4);
  bt[1] = *(const float4*)(bo + cbase + 16 + quad * 4);

  const ushort* ae = ose + (size_t)(blockIdx.x * 64) * 256;
  const ushort* al = osl + (size_t)(blockIdx.x * 64) * 256;

#pragma unroll
  for (int tt = 0; tt < 4; ++tt) {
    short8 xe[8], xl[8];
#pragma unroll
    for (int kc = 0; kc < 8; ++kc)
      xe[kc] = *(const short8*)(ae + (size_t)(tt * 16 + n) * 256 + kc * 32 + quad * 8);
#pragma unroll
    for (int kc = 0; kc < 8; ++kc)
      xl[kc] = *(const short8*)(al + (size_t)(tt * 16 + n) * 256 + kc * 32 + quad * 8);

    int tok = blockIdx.x * 64 + tt * 16 + n;
    f32x4 acc[2] = {{0.f, 0.f, 0.f, 0.f}, {0.f, 0.f, 0.f, 0.f}};
#pragma unroll
    for (int ct = 0; ct < 2; ++ct)
#pragma unroll
      for (int kc = 0; kc < 8; ++kc)
        acc[ct] = __builtin_amdgcn_mfma_f32_16x16x32_bf16(wfrag[ct][kc], xe[kc], acc[ct], 0, 0, 0);
#pragma unroll
    for (int ct = 0; ct < 2; ++ct)
#pragma unroll
      for (int kc = 0; kc < 8; ++kc)
        acc[ct] = __builtin_amdgcn_mfma_f32_16x16x32_bf16(wfrag[ct][kc], xl[kc], acc[ct], 0, 0, 0);
#pragma unroll
    for (int ct = 0; ct < 2; ++ct) {
      int c = cbase + ct * 16 + quad * 4;
      float* bp = (float*)&bt[ct];
      float4 st;
      st.x = acc[ct][0] + 2.0f * bp[0];
      st.y = acc[ct][1] + 2.0f * bp[1];
      st.z = acc[ct][2] + 2.0f * bp[2];
      st.w = acc[ct][3] + 2.0f * bp[3];
      *(float4*)(out + (size_t)tok * 256 + c) = st;
    }
  }
}

extern "C" void kernel_launch(void* const* d_in, const int* in_sizes, int n_in,
                              void* d_out, int out_size, void* d_ws, size_t ws_size,
                              hipStream_t stream) {
  const float* x   = (const float*)d_in[0];
  const float* lng = (const float*)d_in[1];
  const float* lnb = (const float*)d_in[2];
  const float* Wq  = (const float*)d_in[3];
  const float* bq  = (const float*)d_in[4];
  const float* Wk  = (const float*)d_in[5];
  const float* bk  = (const float*)d_in[6];
  const float* Wv  = (const float*)d_in[7];
  const float* bv  = (const float*)d_in[8];
  const float* Wo  = (const float*)d_in[9];
  const float* bo  = (const float*)d_in[10];
  float* out = (float*)d_out;

  ushort* ws = (ushort*)d_ws;
  const size_t XN  = (size_t)49152 * 256;      // 12,582,912
  const size_t QKV = (size_t)64 * 2048 * 32;   //  4,194,304
  ushort* xn     = ws;
  ushort* wbf    = xn + XN;          // [Wq|Wk|Wv|Wo] x 65536
  ushort* qb     = wbf + 4 * 65536;
  ushort* keb    = qb  + QKV;
  ushort* vTe    = keb + QKV;
  ushort* klb    = vTe + QKV;
  ushort* vTl    = klb + QKV;
  ushort* osum_e = vTl + QKV;
  ushort* osum_l = xn;               // alias: xn is dead after proj_kernel

  hipLaunchKernelGGL(ln_wcast_kernel, dim3(12544), dim3(256), 0, stream,
                     x, lng, lnb, Wq, Wk, Wv, Wo, xn, wbf);
  hipLaunchKernelGGL(proj_kernel, dim3(128, 2, 3), dim3(256), 0, stream,
                     xn, wbf, wbf + 65536, wbf + 131072, bq, bk, bv,
                     qb, keb, vTe, klb, vTl);
  hipLaunchKernelGGL(attn_kernel, dim3(8, 256), dim3(256), 0, stream,
                     qb, keb, vTe, klb, vTl, osum_e, osum_l);
  hipLaunchKernelGGL(outproj_kernel, dim3(256, 2), dim3(256), 0, stream,
                     osum_e, osum_l, wbf + 196608, bo, out);
}

// Round 16
// 261.724 us; speedup vs baseline: 1.0801x; 1.0216x over previous
//
#include <hip/hip_runtime.h>
#include <hip/hip_bf16.h>
#include <math.h>

#define LN_EPS 1e-5f
// dim^-0.5 * log2(e): folded into q so softmax is exp2(s) with no muls
#define QSCALE 0.09016844005556021f

typedef __attribute__((ext_vector_type(8))) short short8;
typedef __attribute__((ext_vector_type(4))) short short4v;
typedef __attribute__((ext_vector_type(4))) float f32x4;
typedef __attribute__((ext_vector_type(16))) float f32x16;

__device__ inline ushort f2bf(float f) {
  __hip_bfloat16 h = __float2bfloat16(f);
  return *reinterpret_cast<ushort*>(&h);
}

// pack two positive fp32 into bf16 pair (lo=a, hi=b): +0x8000 then v_perm.
// (hardware-verified; kept for proj epilogues)
__device__ inline uint pk2bf(float a, float b) {
  uint ua = __float_as_uint(a) + 0x8000u;
  uint ub = __float_as_uint(b) + 0x8000u;
  return __builtin_amdgcn_perm(ub, ua, 0x07060302u);
}

// Shapes (fixed): b=8, n=2048/stream, 3 streams, dim=256, heads=8, d=32.
// xn (bf16): [8*6144][256].  q/k (bf16): [bh][2048][32] row-major -- these
//   double as 32x32x16 MFMA A/B fragment sources (row=lane&31, k=hi*8+i).
// vT3 (bf16, 32x32 B-FRAGMENT layout): [bh][64 ktile32][2 u][64 lane][8]:
//   elem = V[key = ktile*32 + 16u + (i&3) + 8*(i>>2) + 4*(lane>>5)]
//            [d = lane&31]  (key perm == 32x32 MFMA C-row pattern, so attn's
//   P-register file feeds PV's A operand with NO data movement).
// osum_e / osum_l (bf16): [b*2048][256] (osum_l aliases dead xn region).
// ROUND 16: r15's cvt_pk fusion cut VALUBusy 63->52 with NO time change --
// attn is residency-bound, not issue-bound.  r11's spill calibrated the
// budget: VGPR_Count excludes AGPRs; current unified ~144-160/wave -> only
// 3 waves/SIMD at the (256,3) cap.  This round: V SINGLE-buffered (load
// inside compute, before QK -- V latency hides under QK+exp; K ping-pong
// KEPT, r4 proved that one load-bearing).  -32 live VGPR -> unified ~112
// <= 128 -> 4 waves/SIMD.  Grids/pack/epilogue byte-identical to r15.

// ---------------------- fused: LN-normalize -> bf16  +  weight cast -> bf16
__global__ __launch_bounds__(256) void ln_wcast_kernel(
    const float* __restrict__ x, const float* __restrict__ lng,
    const float* __restrict__ lnb,
    const float* __restrict__ Wq, const float* __restrict__ Wk,
    const float* __restrict__ Wv, const float* __restrict__ Wo,
    ushort* __restrict__ xn, ushort* __restrict__ wbf) {
  if (blockIdx.x < 256) {
    int t = blockIdx.x * 256 + threadIdx.x;
    int e0 = t * 4;
    int m = e0 >> 16, off = e0 & 65535;
    const float* src = (m == 0) ? Wq : (m == 1) ? Wk : (m == 2) ? Wv : Wo;
    float4 v = *(const float4*)(src + off);
    ushort4 o;
    o.x = f2bf(v.x); o.y = f2bf(v.y); o.z = f2bf(v.z); o.w = f2bf(v.w);
    *(ushort4*)(wbf + m * 65536 + off) = o;
    return;
  }
  int w = threadIdx.x >> 6;
  int lane = threadIdx.x & 63;
  size_t token = (size_t)(blockIdx.x - 256) * 4 + w;
  float4 v = *(const float4*)(x + token * 256 + lane * 4);
  float s  = v.x + v.y + v.z + v.w;
  float s2 = v.x * v.x + v.y * v.y + v.z * v.z + v.w * v.w;
#pragma unroll
  for (int off = 32; off >= 1; off >>= 1) {
    s  += __shfl_xor(s, off, 64);
    s2 += __shfl_xor(s2, off, 64);
  }
  float mu  = s * (1.0f / 256.0f);
  float var = s2 * (1.0f / 256.0f) - mu * mu;
  float rs  = rsqrtf(var + LN_EPS);
  float4 g = *(const float4*)(lng + lane * 4);
  float4 bb = *(const float4*)(lnb + lane * 4);
  ushort4 o;
  o.x = f2bf((v.x - mu) * rs * g.x + bb.x);
  o.y = f2bf((v.y - mu) * rs * g.y + bb.y);
  o.z = f2bf((v.z - mu) * rs * g.z + bb.z);
  o.w = f2bf((v.w - mu) * rs * g.w + bb.w);
  *(ushort4*)(xn + token * 256 + lane * 4) = o;
}

// ------------------------------------------------- QKV projections (MFMA)
// z: 0 = q (stream 0, Wq, scaled, C^T out)
// z: 1 = kv_e, 2 = kv_l: xf loaded ONCE feeds Wk (A-form, C^T) AND Wv
// (B-form, 32x32-fragment vT3 out).  No LDS; xf double-buffered.
// 128 tokens/block (grid 768): r13 config.
__global__ __launch_bounds__(256) void proj_kernel(
    const ushort* __restrict__ xn,
    const ushort* __restrict__ wq, const ushort* __restrict__ wk,
    const ushort* __restrict__ wv,
    const float* __restrict__ bq, const float* __restrict__ bk,
    const float* __restrict__ bv,
    ushort* __restrict__ qb, ushort* __restrict__ keb, ushort* __restrict__ vTe,
    ushort* __restrict__ klb, ushort* __restrict__ vTl) {
  int z = blockIdx.z;
  int tid = threadIdx.x;
  int w = tid >> 6, lane = tid & 63;
  int n = lane & 15, quad = lane >> 4;
  int cbase = blockIdx.y * 128 + w * 32;
  int b = (blockIdx.x * 128) >> 11;
  int r0 = (blockIdx.x * 128) & 2047;

  if (z == 0) {
    const ushort* xbase = xn + ((size_t)b * 6144 + r0) * 256;
    short8 wf[2][8];
#pragma unroll
    for (int ct = 0; ct < 2; ++ct)
#pragma unroll
      for (int kc = 0; kc < 8; ++kc)
        wf[ct][kc] = *(const short8*)(wq + (size_t)(cbase + ct * 16 + n) * 256 + kc * 32 + quad * 8);
    float4 bt[2];
    bt[0] = *(const float4*)(bq + cbase + quad * 4);
    bt[1] = *(const float4*)(bq + cbase + 16 + quad * 4);

    short8 xfA[8], xfB[8];
#pragma unroll
    for (int kc = 0; kc < 8; ++kc)
      xfA[kc] = *(const short8*)(xbase + (size_t)n * 256 + kc * 32 + quad * 8);

#pragma unroll
    for (int tt = 0; tt < 8; ++tt) {
      const short8* cur = (tt & 1) ? xfB : xfA;
      short8* nxt = (tt & 1) ? xfA : xfB;
      if (tt < 7) {
#pragma unroll
        for (int kc = 0; kc < 8; ++kc)
          nxt[kc] = *(const short8*)(xbase + (size_t)((tt + 1) * 16 + n) * 256 + kc * 32 + quad * 8);
      }
      f32x4 acc[2] = {{0.f, 0.f, 0.f, 0.f}, {0.f, 0.f, 0.f, 0.f}};
#pragma unroll
      for (int ct = 0; ct < 2; ++ct)
#pragma unroll
        for (int kc = 0; kc < 8; ++kc)
          acc[ct] = __builtin_amdgcn_mfma_f32_16x16x32_bf16(wf[ct][kc], cur[kc], acc[ct], 0, 0, 0);
      int n2 = r0 + tt * 16 + n;
#pragma unroll
      for (int ct = 0; ct < 2; ++ct) {
        int c = cbase + ct * 16 + quad * 4;
        int h = c >> 5, d = c & 31;
        float* bp = (float*)&bt[ct];
        ushort4 st;
        st.x = f2bf((acc[ct][0] + bp[0]) * QSCALE);
        st.y = f2bf((acc[ct][1] + bp[1]) * QSCALE);
        st.z = f2bf((acc[ct][2] + bp[2]) * QSCALE);
        st.w = f2bf((acc[ct][3] + bp[3]) * QSCALE);
        *(ushort4*)(qb + (((size_t)(b * 8 + h) * 2048) + n2) * 32 + d) = st;
      }
    }
  } else {
    int s = z;
    ushort* kout = (z == 1) ? keb : klb;
    ushort* vout = (z == 1) ? vTe : vTl;
    const ushort* xbase = xn + ((size_t)b * 6144 + s * 2048 + r0) * 256;
    short8 wfk[2][8], wfv[2][8];
#pragma unroll
    for (int ct = 0; ct < 2; ++ct)
#pragma unroll
      for (int kc = 0; kc < 8; ++kc) {
        wfk[ct][kc] = *(const short8*)(wk + (size_t)(cbase + ct * 16 + n) * 256 + kc * 32 + quad * 8);
        wfv[ct][kc] = *(const short8*)(wv + (size_t)(cbase + ct * 16 + n) * 256 + kc * 32 + quad * 8);
      }
    float4 btk[2];
    btk[0] = *(const float4*)(bk + cbase + quad * 4);
    btk[1] = *(const float4*)(bk + cbase + 16 + quad * 4);
    float bsv[2] = {bv[cbase + n], bv[cbase + 16 + n]};

    short8 xfA[8], xfB[8];
#pragma unroll
    for (int kc = 0; kc < 8; ++kc)
      xfA[kc] = *(const short8*)(xbase + (size_t)n * 256 + kc * 32 + quad * 8);

#pragma unroll
    for (int tt = 0; tt < 8; ++tt) {
      const short8* cur = (tt & 1) ? xfB : xfA;
      short8* nxt = (tt & 1) ? xfA : xfB;
      if (tt < 7) {
#pragma unroll
        for (int kc = 0; kc < 8; ++kc)
          nxt[kc] = *(const short8*)(xbase + (size_t)((tt + 1) * 16 + n) * 256 + kc * 32 + quad * 8);
      }
      f32x4 ack[2] = {{0.f, 0.f, 0.f, 0.f}, {0.f, 0.f, 0.f, 0.f}};
      f32x4 acv[2] = {{0.f, 0.f, 0.f, 0.f}, {0.f, 0.f, 0.f, 0.f}};
#pragma unroll
      for (int ct = 0; ct < 2; ++ct)
#pragma unroll
        for (int kc = 0; kc < 8; ++kc) {
          ack[ct] = __builtin_amdgcn_mfma_f32_16x16x32_bf16(wfk[ct][kc], cur[kc], ack[ct], 0, 0, 0);
          acv[ct] = __builtin_amdgcn_mfma_f32_16x16x32_bf16(cur[kc], wfv[ct][kc], acv[ct], 0, 0, 0);
        }
      // store k: C^T row-major [bh][2048][32] (lane: token n2, cols quad*4+r)
      int n2 = r0 + tt * 16 + n;
#pragma unroll
      for (int ct = 0; ct < 2; ++ct) {
        int c = cbase + ct * 16 + quad * 4;
        int h = c >> 5, d = c & 31;
        float* bp = (float*)&btk[ct];
        ushort4 st;
        st.x = f2bf(ack[ct][0] + bp[0]);
        st.y = f2bf(ack[ct][1] + bp[1]);
        st.z = f2bf(ack[ct][2] + bp[2]);
        st.w = f2bf(ack[ct][3] + bp[3]);
        *(ushort4*)(kout + (((size_t)(b * 8 + h) * 2048) + n2) * 32 + d) = st;
      }
      // store v: 32x32 B-fragment layout vT3[bh][ktile][u][lane2][8].
      // acv reg r is token tq+r; kappa = quad*4+r -> hi2=quad&1,
      // i = r + 4*(quad>>1)  (8*(quad>>1)+4*(quad&1) == 4*quad)
      int tq = r0 + tt * 16 + quad * 4;
      int ktile = tq >> 5;
      int u = (tq >> 4) & 1;
      int i0 = 4 * (quad >> 1);
      int hi2 = quad & 1;
#pragma unroll
      for (int ct = 0; ct < 2; ++ct) {
        int c = cbase + ct * 16 + n;
        int h = c >> 5;
        int d = ct * 16 + n;          // c & 31 (cbase is 32-aligned)
        int lane2 = d + 32 * hi2;
        ushort4 st;
        st.x = f2bf(acv[ct][0] + bsv[ct]);
        st.y = f2bf(acv[ct][1] + bsv[ct]);
        st.z = f2bf(acv[ct][2] + bsv[ct]);
        st.w = f2bf(acv[ct][3] + bsv[ct]);
        *(ushort4*)(vout + (size_t)(b * 8 + h) * 65536
                    + ktile * 1024 + u * 512 + lane2 * 8 + i0) = st;
      }
    }
  }
}

// ------------------------------------------------ flash attention bf16 MFMA
// 32x32x16; tree-sum denominator; 2 PV accumulators; fence-free hoisted QK;
// scalar-f2bf pack (fuses to v_cvt_pk).  ROUND 16: V single-buffered --
// loaded inside compute() BEFORE the QK MFMAs, consumed by PV ~250cy later
// (QK 4 MFMAs + exp/pack cover the L1/L2 hit latency).  K ping-pong kept.
// -32 live VGPR -> unified budget ~112 <= 128 -> 4 waves/SIMD.
__global__ __launch_bounds__(256, 3) void attn_kernel(
    const ushort* __restrict__ q,
    const ushort* __restrict__ ke, const ushort* __restrict__ vTe,
    const ushort* __restrict__ kl, const ushort* __restrict__ vTl,
    ushort* __restrict__ osum_e, ushort* __restrict__ osum_l) {
  int tid = threadIdx.x;
  int w = tid >> 6, lane = tid & 63;
  int l31 = lane & 31, hi = lane >> 5;

  int L = blockIdx.y * 8 + blockIdx.x;
  int xcd = L & 7, idx = L >> 3;          // idx in [0,256)
  int bh = (idx >> 5) * 8 + xcd;
  int rem = idx & 31;
  int s = rem >> 4;                        // stream 0=e, 1=l
  int q0 = (rem & 15) * 128;
  int qbase = q0 + w * 32;

  const ushort* K  = (s == 0 ? ke : kl) + (size_t)bh * 65536;
  const ushort* VT = (s == 0 ? vTe : vTl) + (size_t)bh * 65536;
  ushort* osum = (s == 0) ? osum_e : osum_l;

  short8 qf[2];
#pragma unroll
  for (int sl = 0; sl < 2; ++sl)
    qf[sl] = *(const short8*)(q + ((size_t)bh * 2048 + qbase + l31) * 32 + sl * 16 + hi * 8);

  f32x16 zero16;
#pragma unroll
  for (int r = 0; r < 16; ++r) zero16[r] = 0.f;
  f32x16 oa0 = zero16, oa1 = zero16;   // two independent PV accumulators
  float lsum = 0.f;

  auto loadK = [&](short8* kf, int jt) {
    const ushort* kb = K + (size_t)jt * 2048;   // 64 keys * 32 d
#pragma unroll
    for (int kt = 0; kt < 2; ++kt)
#pragma unroll
      for (int sl = 0; sl < 2; ++sl)
        kf[kt * 2 + sl] = *(const short8*)(kb + (kt * 32 + l31) * 32 + sl * 16 + hi * 8);
  };

  // finish one kt-half: exp -> lsum tree -> pack (scalar f2bf: compiler
  // fuses to v_cvt_pk_bf16_f32) -> PV (2 MFMAs)
  auto finish = [&](const f32x16& sacc, const short8* vf2) {
    float p[16];
#pragma unroll
    for (int r = 0; r < 16; ++r) p[r] = __builtin_amdgcn_exp2f(sacc[r]);
    float t0 = (p[0] + p[1]) + (p[2] + p[3]);
    float t1 = (p[4] + p[5]) + (p[6] + p[7]);
    float t2 = (p[8] + p[9]) + (p[10] + p[11]);
    float t3 = (p[12] + p[13]) + (p[14] + p[15]);
    lsum += (t0 + t1) + (t2 + t3);
    short8 pa0, pa1;
    {
      union { ushort u[8]; short8 s8; } cv;
#pragma unroll
      for (int j = 0; j < 8; ++j) cv.u[j] = f2bf(p[j]);
      pa0 = cv.s8;
    }
    {
      union { ushort u[8]; short8 s8; } cv;
#pragma unroll
      for (int j = 0; j < 8; ++j) cv.u[j] = f2bf(p[8 + j]);
      pa1 = cv.s8;
    }
    oa0 = __builtin_amdgcn_mfma_f32_32x32x16_bf16(pa0, vf2[0], oa0, 0, 0, 0);
    oa1 = __builtin_amdgcn_mfma_f32_32x32x16_bf16(pa1, vf2[1], oa1, 0, 0, 0);
  };

  // V loaded HERE (single-buffered): issued before QK, consumed by PV
  // after QK+exp+pack -- load latency covered within the iteration.
  auto compute = [&](const short8* kf, int jt) {
    short8 vf[4];
    const ushort* vb = VT + (size_t)jt * 2048 + lane * 8;
#pragma unroll
    for (int m = 0; m < 4; ++m)                 // m = kt*2+u
      vf[m] = *(const short8*)(vb + m * 512);
    f32x16 sacc0 = __builtin_amdgcn_mfma_f32_32x32x16_bf16(kf[0], qf[0], zero16, 0, 0, 0);
    sacc0 = __builtin_amdgcn_mfma_f32_32x32x16_bf16(kf[1], qf[1], sacc0, 0, 0, 0);
    f32x16 sacc1 = __builtin_amdgcn_mfma_f32_32x32x16_bf16(kf[2], qf[0], zero16, 0, 0, 0);
    sacc1 = __builtin_amdgcn_mfma_f32_32x32x16_bf16(kf[3], qf[1], sacc1, 0, 0, 0);
    finish(sacc0, vf + 0);
    finish(sacc1, vf + 2);
  };

  short8 kfA[4], kfB[4];
  loadK(kfA, 0);
  for (int jt = 0; jt < 32; jt += 2) {
    loadK(kfB, jt + 1);          // in flight during compute(A)
    compute(kfA, jt);
    if (jt + 2 < 32) loadK(kfA, jt + 2);
    compute(kfB, jt + 1);
  }

  // denominator: lanes l and l^32 hold complementary key-halves of q=l31
  lsum += __shfl_xor(lsum, 32, 64);
  float inv = __builtin_amdgcn_rcpf(lsum);

  int b = bh >> 3, h = bh & 7;
#pragma unroll
  for (int r = 0; r < 16; ++r) {
    int qr = (r & 3) + 8 * (r >> 2) + 4 * hi;
    float invr = __shfl(inv, qr, 64);
    float v = (oa0[r] + oa1[r]) * invr;
    size_t row = (size_t)b * 2048 + qbase + qr;
    osum[row * 256 + h * 32 + l31] = f2bf(v);
  }
}

// ------------------------------------------- output projection (MFMA, C^T)
// out[t][c] = sum_k (ose[t][k]+osl[t][k])*Wo[c][k] + 2*bo[c]: both streams
// accumulated into the same MFMA C (K=512).  64-row blocks (grid 512, r13).
__global__ __launch_bounds__(256) void outproj_kernel(
    const ushort* __restrict__ ose, const ushort* __restrict__ osl,
    const ushort* __restrict__ wo,
    const float* __restrict__ bo, float* __restrict__ out) {
  int tid = threadIdx.x;
  int w = tid >> 6, lane = tid & 63;
  int n = lane & 15, quad = lane >> 4;
  int cbase = blockIdx.y * 128 + w * 32;

  short8 wfrag[2][8];
#pragma unroll
  for (int ct = 0; ct < 2; ++ct)
#pragma unroll
    for (int kc = 0; kc < 8; ++kc)
      wfrag[ct][kc] = *(const short8*)(wo + (size_t)(cbase + ct * 16 + n) * 256 + kc * 32 + quad * 8);
  float4 bt[2];
  bt[0] = *(const float4*)(bo + cbase + quad * 4);
  bt[1] = *(const float4*)(bo + cbase + 16 + quad * 4);

  const ushort* ae = ose + (size_t)(blockIdx.x * 64) * 256;
  const ushort* al = osl + (size_t)(blockIdx.x * 64) * 256;

#pragma unroll
  for (int tt = 0; tt < 4; ++tt) {
    short8 xe[8], xl[8];
#pragma unroll
    for (int kc = 0; kc < 8; ++kc)
      xe[kc] = *(const short8*)(ae + (size_t)(tt * 16 + n) * 256 + kc * 32 + quad * 8);
#pragma unroll
    for (int kc = 0; kc < 8; ++kc)
      xl[kc] = *(const short8*)(al + (size_t)(tt * 16 + n) * 256 + kc * 32 + quad * 8);

    int tok = blockIdx.x * 64 + tt * 16 + n;
    f32x4 acc[2] = {{0.f, 0.f, 0.f, 0.f}, {0.f, 0.f, 0.f, 0.f}};
#pragma unroll
    for (int ct = 0; ct < 2; ++ct)
#pragma unroll
      for (int kc = 0; kc < 8; ++kc)
        acc[ct] = __builtin_amdgcn_mfma_f32_16x16x32_bf16(wfrag[ct][kc], xe[kc], acc[ct], 0, 0, 0);
#pragma unroll
    for (int ct = 0; ct < 2; ++ct)
#pragma unroll
      for (int kc = 0; kc < 8; ++kc)
        acc[ct] = __builtin_amdgcn_mfma_f32_16x16x32_bf16(wfrag[ct][kc], xl[kc], acc[ct], 0, 0, 0);
#pragma unroll
    for (int ct = 0; ct < 2; ++ct) {
      int c = cbase + ct * 16 + quad * 4;
      float* bp = (float*)&bt[ct];
      float4 st;
      st.x = acc[ct][0] + 2.0f * bp[0];
      st.y = acc[ct][1] + 2.0f * bp[1];
      st.z = acc[ct][2] + 2.0f * bp[2];
      st.w = acc[ct][3] + 2.0f * bp[3];
      *(float4*)(out + (size_t)tok * 256 + c) = st;
    }
  }
}

extern "C" void kernel_launch(void* const* d_in, const int* in_sizes, int n_in,
                              void* d_out, int out_size, void* d_ws, size_t ws_size,
                              hipStream_t stream) {
  const float* x   = (const float*)d_in[0];
  const float* lng = (const float*)d_in[1];
  const float* lnb = (const float*)d_in[2];
  const float* Wq  = (const float*)d_in[3];
  const float* bq  = (const float*)d_in[4];
  const float* Wk  = (const float*)d_in[5];
  const float* bk  = (const float*)d_in[6];
  const float* Wv  = (const float*)d_in[7];
  const float* bv  = (const float*)d_in[8];
  const float* Wo  = (const float*)d_in[9];
  const float* bo  = (const float*)d_in[10];
  float* out = (float*)d_out;

  ushort* ws = (ushort*)d_ws;
  const size_t XN  = (size_t)49152 * 256;      // 12,582,912
  const size_t QKV = (size_t)64 * 2048 * 32;   //  4,194,304
  ushort* xn     = ws;
  ushort* wbf    = xn + XN;          // [Wq|Wk|Wv|Wo] x 65536
  ushort* qb     = wbf + 4 * 65536;
  ushort* keb    = qb  + QKV;
  ushort* vTe    = keb + QKV;
  ushort* klb    = vTe + QKV;
  ushort* vTl    = klb + QKV;
  ushort* osum_e = vTl + QKV;
  ushort* osum_l = xn;               // alias: xn is dead after proj_kernel

  hipLaunchKernelGGL(ln_wcast_kernel, dim3(12544), dim3(256), 0, stream,
                     x, lng, lnb, Wq, Wk, Wv, Wo, xn, wbf);
  hipLaunchKernelGGL(proj_kernel, dim3(128, 2, 3), dim3(256), 0, stream,
                     xn, wbf, wbf + 65536, wbf + 131072, bq, bk, bv,
                     qb, keb, vTe, klb, vTl);
  hipLaunchKernelGGL(attn_kernel, dim3(8, 256), dim3(256), 0, stream,
                     qb, keb, vTe, klb, vTl, osum_e, osum_l);
  hipLaunchKernelGGL(outproj_kernel, dim3(256, 2), dim3(256), 0, stream,
                     osum_e, osum_l, wbf + 196608, bo, out);
}